// Round 1
// baseline (171.340 us; speedup 1.0000x reference)
//
#include <hip/hip_runtime.h>
#include <math.h>
#include <stdint.h>

#define NS 200
#define THASH (1 << 19)
#define TMASK ((1u << 19) - 1u)

__device__ __forceinline__ float sigmoidf_(float v) {
    return 1.0f / (1.0f + __expf(-v));
}

// Trilinear hash-grid lookup, D=1 table.
__device__ __forceinline__ float trilerp1(const float* __restrict__ tbl,
                                          float xf, float yf, float zf) {
    const uint32_t P2 = 2654435761u, P3 = 805459861u;
    float fx = floorf(xf), fy = floorf(yf), fz = floorf(zf);
    float wx = xf - fx, wy = yf - fy, wz = zf - fz;
    uint32_t x0 = (uint32_t)(int)fx, y0 = (uint32_t)(int)fy, z0 = (uint32_t)(int)fz;
    uint32_t hx0 = x0, hx1 = x0 + 1u;
    uint32_t hy0 = y0 * P2, hy1 = (y0 + 1u) * P2;
    uint32_t hz0 = z0 * P3, hz1 = (z0 + 1u) * P3;
    float v000 = tbl[(hx0 ^ hy0 ^ hz0) & TMASK];
    float v001 = tbl[(hx0 ^ hy0 ^ hz1) & TMASK];
    float v010 = tbl[(hx0 ^ hy1 ^ hz0) & TMASK];
    float v011 = tbl[(hx0 ^ hy1 ^ hz1) & TMASK];
    float v100 = tbl[(hx1 ^ hy0 ^ hz0) & TMASK];
    float v101 = tbl[(hx1 ^ hy0 ^ hz1) & TMASK];
    float v110 = tbl[(hx1 ^ hy1 ^ hz0) & TMASK];
    float v111 = tbl[(hx1 ^ hy1 ^ hz1) & TMASK];
    float ux = 1.0f - wx, uy = 1.0f - wy, uz = 1.0f - wz;
    return v000 * (ux * uy * uz) + v001 * (ux * uy * wz) +
           v010 * (ux * wy * uz) + v011 * (ux * wy * wz) +
           v100 * (wx * uy * uz) + v101 * (wx * uy * wz) +
           v110 * (wx * wy * uz) + v111 * (wx * wy * wz);
}

// Kernel 1: one block (256 threads) per ray. Lane s computes label[b,s];
// block-reduce max (hits) and first index with label>0.5 (first).
__global__ __launch_bounds__(256) void k_label(
        const float* __restrict__ x,
        const float* __restrict__ tlab,
        const float* __restrict__ wlab, const float* __restrict__ blab,
        float* __restrict__ hits, float* __restrict__ labels,
        int* __restrict__ firsts)
{
    const int b = blockIdx.x;
    const int s = threadIdx.x;
    const float4 ray = *(const float4*)(x + 4 * (size_t)b);

    float lab = -1.0f;
    int cand = NS;
    if (s < NS) {
        const float t = (float)s * (1.0f / 199.0f);
        const float px = ray.x * (1.0f - t) + ray.z * t;
        const float py = ray.y * (1.0f - t) + ray.w * t;
        const float pz = t;
        float acc = blab[0];
        #pragma unroll
        for (int l = 0; l < 5; ++l) {
            const int res = 8 << l;
            const float v = trilerp1(tlab + (size_t)l * THASH,
                                     px * (float)res, py * (float)res, pz * (float)res);
            acc = fmaf(v, wlab[l], acc);
        }
        lab = sigmoidf_(acc);
        labels[(size_t)b * NS + s] = lab;
        if (lab > 0.5f) cand = s;
    }

    __shared__ float smax[256];
    __shared__ int smin[256];
    smax[s] = lab;
    smin[s] = cand;
    __syncthreads();
    for (int off = 128; off > 0; off >>= 1) {
        if (s < off) {
            smax[s] = fmaxf(smax[s], smax[s + off]);
            smin[s] = min(smin[s], smin[s + off]);
        }
        __syncthreads();
    }
    if (s == 0) {
        hits[b] = smax[0];
        firsts[b] = (smin[0] >= NS) ? 0 : smin[0];
    }
}

// Kernel 2: 256 threads = 4 waves; each wave handles one ray.
// Phase A: 30 (sample,level) pairs x 8 corners = 240 float4 gathers -> feat[120].
// Phase B: MLP 120->64->64->64->3.
__global__ __launch_bounds__(256) void k_rgb(
        const float* __restrict__ x,
        const float* __restrict__ trgb,
        const int* __restrict__ firsts,
        const float* __restrict__ W1, const float* __restrict__ b1,
        const float* __restrict__ W2, const float* __restrict__ b2,
        const float* __restrict__ W3, const float* __restrict__ b3,
        const float* __restrict__ W4, const float* __restrict__ b4,
        float* __restrict__ rgb)
{
    const uint32_t P2 = 2654435761u, P3 = 805459861u;
    const int wid = threadIdx.x >> 6;
    const int lane = threadIdx.x & 63;
    const int b = blockIdx.x * 4 + wid;

    __shared__ float feat[4][120];
    __shared__ float hs[4][64];

    const float4 ray = *(const float4*)(x + 4 * (size_t)b);
    const int first = firsts[b];

    const int corner = lane & 7;   // corner within cell
    const int group = lane >> 3;   // which (sample,level) pair in this batch
    const int bi = (corner >> 2) & 1, bj = (corner >> 1) & 1, bk = corner & 1;

    for (int it = 0; it < 4; ++it) {
        const int pair = it * 8 + group;  // 0..31 (30 used)
        float vx = 0.f, vy = 0.f, vz = 0.f, vw = 0.f;
        if (pair < 30) {
            const int si = pair / 6;      // offset index 0..4  (first+si-2)
            const int l = pair % 6;       // level 0..5
            int sc = first + si - 2;
            sc = sc < 0 ? 0 : (sc > NS - 1 ? NS - 1 : sc);
            const float t = (float)sc * (1.0f / 199.0f);
            const float px = ray.x * (1.0f - t) + ray.z * t;
            const float py = ray.y * (1.0f - t) + ray.w * t;
            const float pz = t;
            const int res = 4 << l;
            const float xf = px * (float)res, yf = py * (float)res, zf = pz * (float)res;
            const float fx = floorf(xf), fy = floorf(yf), fz = floorf(zf);
            const float wx = xf - fx, wy = yf - fy, wz = zf - fz;
            const uint32_t x0 = (uint32_t)(int)fx, y0 = (uint32_t)(int)fy, z0 = (uint32_t)(int)fz;
            const uint32_t hx = x0 + (uint32_t)bi;
            const uint32_t hy = (y0 + (uint32_t)bj) * P2;
            const uint32_t hz = (z0 + (uint32_t)bk) * P3;
            const uint32_t idx = (hx ^ hy ^ hz) & TMASK;
            const float cw = (bi ? wx : 1.0f - wx) * (bj ? wy : 1.0f - wy) * (bk ? wz : 1.0f - wz);
            const float4 tv = *(const float4*)(trgb + (((size_t)l << 19) + idx) * 4);
            vx = tv.x * cw; vy = tv.y * cw; vz = tv.z * cw; vw = tv.w * cw;
        }
        // sum the 8 corners (8 consecutive lanes)
        #pragma unroll
        for (int m = 1; m < 8; m <<= 1) {
            vx += __shfl_xor(vx, m);
            vy += __shfl_xor(vy, m);
            vz += __shfl_xor(vz, m);
            vw += __shfl_xor(vw, m);
        }
        if (corner == 0 && pair < 30) {
            const int si = pair / 6, l = pair % 6;
            float* f = &feat[wid][si * 24 + l * 4];
            f[0] = vx; f[1] = vy; f[2] = vz; f[3] = vw;
        }
    }
    __syncthreads();

    // ---- MLP ----
    const float* fw = feat[wid];
    float acc = b1[lane];
    #pragma unroll 8
    for (int i = 0; i < 120; ++i) acc = fmaf(fw[i], W1[i * 64 + lane], acc);
    float h = fmaxf(acc, 0.0f);

    acc = b2[lane];
    #pragma unroll 8
    for (int i = 0; i < 64; ++i) acc = fmaf(__shfl(h, i), W2[i * 64 + lane], acc);
    h = fmaxf(acc, 0.0f);

    acc = b3[lane];
    #pragma unroll 8
    for (int i = 0; i < 64; ++i) acc = fmaf(__shfl(h, i), W3[i * 64 + lane], acc);
    h = fmaxf(acc, 0.0f);

    hs[wid][lane] = h;
    __syncthreads();
    if (lane < 3) {
        float r = b4[lane];
        #pragma unroll 8
        for (int j = 0; j < 64; ++j) r = fmaf(hs[wid][j], W4[j * 3 + lane], r);
        rgb[(size_t)b * 3 + lane] = r;
    }
}

extern "C" void kernel_launch(void* const* d_in, const int* in_sizes, int n_in,
                              void* d_out, int out_size, void* d_ws, size_t ws_size,
                              hipStream_t stream) {
    const float* x    = (const float*)d_in[0];
    const float* tlab = (const float*)d_in[1];
    const float* trgb = (const float*)d_in[2];
    const float* wlab = (const float*)d_in[3];
    const float* blab = (const float*)d_in[4];
    const float* W1   = (const float*)d_in[5];
    const float* b1   = (const float*)d_in[6];
    const float* W2   = (const float*)d_in[7];
    const float* b2   = (const float*)d_in[8];
    const float* W3   = (const float*)d_in[9];
    const float* b3   = (const float*)d_in[10];
    const float* W4   = (const float*)d_in[11];
    const float* b4   = (const float*)d_in[12];

    const int B = in_sizes[0] / 4;  // 16384

    float* hits   = (float*)d_out;                       // [B]
    float* labels = hits + B;                            // [B*NS]
    float* rgbout = labels + (size_t)B * NS;             // [B*3]
    int* firsts   = (int*)d_ws;                          // [B]

    k_label<<<B, 256, 0, stream>>>(x, tlab, wlab, blab, hits, labels, firsts);
    k_rgb<<<B / 4, 256, 0, stream>>>(x, trgb, firsts,
                                     W1, b1, W2, b2, W3, b3, W4, b4, rgbout);
}

// Round 2
// 166.920 us; speedup vs baseline: 1.0265x; 1.0265x over previous
//
#include <hip/hip_runtime.h>
#include <math.h>
#include <stdint.h>

#define NS 200
#define THASH (1 << 19)
#define TMASK ((1u << 19) - 1u)

__device__ __forceinline__ float sigmoidf_(float v) {
    return 1.0f / (1.0f + __expf(-v));
}

// Kernel 1: one block (256 threads) per ray. Lane s computes label[b,s].
// All 40 hash-grid gathers are issued before any consumption (single
// latency exposure instead of 5 serial round-trips).
__global__ __launch_bounds__(256) void k_label(
        const float* __restrict__ x,
        const float* __restrict__ tlab,
        const float* __restrict__ wlab, const float* __restrict__ blab,
        float* __restrict__ hits, float* __restrict__ labels,
        int* __restrict__ firsts)
{
    const uint32_t P2 = 2654435761u, P3 = 805459861u;
    const int b = blockIdx.x;
    const int s = threadIdx.x;
    const float4 ray = *(const float4*)(x + 4 * (size_t)b);

    float lab = -1.0f;
    int cand = NS;

    float vals[40];
    float wxs[5], wys[5], wzs[5];

    if (s < NS) {
        const float t = (float)s * (1.0f / 199.0f);
        const float px = ray.x * (1.0f - t) + ray.z * t;
        const float py = ray.y * (1.0f - t) + ray.w * t;
        const float pz = t;

        // ---- issue ALL 40 gathers ----
        #pragma unroll
        for (int l = 0; l < 5; ++l) {
            const float res = (float)(8 << l);
            const float xf = px * res, yf = py * res, zf = pz * res;
            const float fx = floorf(xf), fy = floorf(yf), fz = floorf(zf);
            wxs[l] = xf - fx; wys[l] = yf - fy; wzs[l] = zf - fz;
            const uint32_t x0 = (uint32_t)(int)fx;
            const uint32_t y0 = (uint32_t)(int)fy;
            const uint32_t z0 = (uint32_t)(int)fz;
            const uint32_t hx0 = x0,       hx1 = x0 + 1u;
            const uint32_t hy0 = y0 * P2,  hy1 = hy0 + P2;
            const uint32_t hz0 = z0 * P3,  hz1 = hz0 + P3;
            const float* __restrict__ tl = tlab + (size_t)l * THASH;
            vals[l * 8 + 0] = tl[(hx0 ^ hy0 ^ hz0) & TMASK];
            vals[l * 8 + 1] = tl[(hx0 ^ hy0 ^ hz1) & TMASK];
            vals[l * 8 + 2] = tl[(hx0 ^ hy1 ^ hz0) & TMASK];
            vals[l * 8 + 3] = tl[(hx0 ^ hy1 ^ hz1) & TMASK];
            vals[l * 8 + 4] = tl[(hx1 ^ hy0 ^ hz0) & TMASK];
            vals[l * 8 + 5] = tl[(hx1 ^ hy0 ^ hz1) & TMASK];
            vals[l * 8 + 6] = tl[(hx1 ^ hy1 ^ hz0) & TMASK];
            vals[l * 8 + 7] = tl[(hx1 ^ hy1 ^ hz1) & TMASK];
        }

        // ---- consume: 7 lerps per level ----
        float acc = blab[0];
        #pragma unroll
        for (int l = 0; l < 5; ++l) {
            const float wx = wxs[l], wy = wys[l], wz = wzs[l];
            const float* v = &vals[l * 8];
            const float c00 = fmaf(wz, v[1] - v[0], v[0]);
            const float c01 = fmaf(wz, v[3] - v[2], v[2]);
            const float c10 = fmaf(wz, v[5] - v[4], v[4]);
            const float c11 = fmaf(wz, v[7] - v[6], v[6]);
            const float c0 = fmaf(wy, c01 - c00, c00);
            const float c1 = fmaf(wy, c11 - c10, c10);
            const float cv = fmaf(wx, c1 - c0, c0);
            acc = fmaf(cv, wlab[l], acc);
        }
        lab = sigmoidf_(acc);
        labels[(size_t)b * NS + s] = lab;
        if (lab > 0.5f) cand = s;
    }

    __shared__ float smax[256];
    __shared__ int smin[256];
    smax[s] = lab;
    smin[s] = cand;
    __syncthreads();
    for (int off = 128; off > 0; off >>= 1) {
        if (s < off) {
            smax[s] = fmaxf(smax[s], smax[s + off]);
            smin[s] = min(smin[s], smin[s + off]);
        }
        __syncthreads();
    }
    if (s == 0) {
        hits[b] = smax[0];
        firsts[b] = (smin[0] >= NS) ? 0 : smin[0];
    }
}

// Kernel 2: 256 threads = 4 waves; each wave handles one ray.
__global__ __launch_bounds__(256) void k_rgb(
        const float* __restrict__ x,
        const float* __restrict__ trgb,
        const int* __restrict__ firsts,
        const float* __restrict__ W1, const float* __restrict__ b1,
        const float* __restrict__ W2, const float* __restrict__ b2,
        const float* __restrict__ W3, const float* __restrict__ b3,
        const float* __restrict__ W4, const float* __restrict__ b4,
        float* __restrict__ rgb)
{
    const uint32_t P2 = 2654435761u, P3 = 805459861u;
    const int wid = threadIdx.x >> 6;
    const int lane = threadIdx.x & 63;
    const int b = blockIdx.x * 4 + wid;

    __shared__ float feat[4][120];
    __shared__ float hs[4][64];

    const float4 ray = *(const float4*)(x + 4 * (size_t)b);
    const int first = firsts[b];

    const int corner = lane & 7;
    const int group = lane >> 3;
    const int bi = (corner >> 2) & 1, bj = (corner >> 1) & 1, bk = corner & 1;

    #pragma unroll
    for (int it = 0; it < 4; ++it) {
        const int pair = it * 8 + group;  // 0..31 (30 used)
        float vx = 0.f, vy = 0.f, vz = 0.f, vw = 0.f;
        if (pair < 30) {
            const int si = pair / 6;
            const int l = pair % 6;
            int sc = first + si - 2;
            sc = sc < 0 ? 0 : (sc > NS - 1 ? NS - 1 : sc);
            const float t = (float)sc * (1.0f / 199.0f);
            const float px = ray.x * (1.0f - t) + ray.z * t;
            const float py = ray.y * (1.0f - t) + ray.w * t;
            const float pz = t;
            const int res = 4 << l;
            const float xf = px * (float)res, yf = py * (float)res, zf = pz * (float)res;
            const float fx = floorf(xf), fy = floorf(yf), fz = floorf(zf);
            const float wx = xf - fx, wy = yf - fy, wz = zf - fz;
            const uint32_t x0 = (uint32_t)(int)fx, y0 = (uint32_t)(int)fy, z0 = (uint32_t)(int)fz;
            const uint32_t hx = x0 + (uint32_t)bi;
            const uint32_t hy = (y0 + (uint32_t)bj) * P2;
            const uint32_t hz = (z0 + (uint32_t)bk) * P3;
            const uint32_t idx = (hx ^ hy ^ hz) & TMASK;
            const float cw = (bi ? wx : 1.0f - wx) * (bj ? wy : 1.0f - wy) * (bk ? wz : 1.0f - wz);
            const float4 tv = *(const float4*)(trgb + (((size_t)l << 19) + idx) * 4);
            vx = tv.x * cw; vy = tv.y * cw; vz = tv.z * cw; vw = tv.w * cw;
        }
        #pragma unroll
        for (int m = 1; m < 8; m <<= 1) {
            vx += __shfl_xor(vx, m);
            vy += __shfl_xor(vy, m);
            vz += __shfl_xor(vz, m);
            vw += __shfl_xor(vw, m);
        }
        if (corner == 0 && pair < 30) {
            const int si = pair / 6, l = pair % 6;
            float* f = &feat[wid][si * 24 + l * 4];
            f[0] = vx; f[1] = vy; f[2] = vz; f[3] = vw;
        }
    }
    __syncthreads();

    // ---- MLP: layer 1 (120 -> 64), float4 LDS broadcast + 4 accumulators ----
    const float* fw = feat[wid];
    float a0 = b1[lane], a1 = 0.f, a2 = 0.f, a3 = 0.f;
    #pragma unroll
    for (int i = 0; i < 120; i += 4) {
        const float4 fv = *(const float4*)(fw + i);
        a0 = fmaf(fv.x, W1[(i + 0) * 64 + lane], a0);
        a1 = fmaf(fv.y, W1[(i + 1) * 64 + lane], a1);
        a2 = fmaf(fv.z, W1[(i + 2) * 64 + lane], a2);
        a3 = fmaf(fv.w, W1[(i + 3) * 64 + lane], a3);
    }
    float h = fmaxf((a0 + a1) + (a2 + a3), 0.0f);

    // ---- layer 2 (64 -> 64) via LDS broadcast ----
    hs[wid][lane] = h;
    __syncthreads();
    a0 = b2[lane]; a1 = 0.f; a2 = 0.f; a3 = 0.f;
    #pragma unroll
    for (int i = 0; i < 64; i += 4) {
        const float4 hv = *(const float4*)(&hs[wid][i]);
        a0 = fmaf(hv.x, W2[(i + 0) * 64 + lane], a0);
        a1 = fmaf(hv.y, W2[(i + 1) * 64 + lane], a1);
        a2 = fmaf(hv.z, W2[(i + 2) * 64 + lane], a2);
        a3 = fmaf(hv.w, W2[(i + 3) * 64 + lane], a3);
    }
    h = fmaxf((a0 + a1) + (a2 + a3), 0.0f);

    // ---- layer 3 (64 -> 64) ----
    __syncthreads();
    hs[wid][lane] = h;
    __syncthreads();
    a0 = b3[lane]; a1 = 0.f; a2 = 0.f; a3 = 0.f;
    #pragma unroll
    for (int i = 0; i < 64; i += 4) {
        const float4 hv = *(const float4*)(&hs[wid][i]);
        a0 = fmaf(hv.x, W3[(i + 0) * 64 + lane], a0);
        a1 = fmaf(hv.y, W3[(i + 1) * 64 + lane], a1);
        a2 = fmaf(hv.z, W3[(i + 2) * 64 + lane], a2);
        a3 = fmaf(hv.w, W3[(i + 3) * 64 + lane], a3);
    }
    h = fmaxf((a0 + a1) + (a2 + a3), 0.0f);

    // ---- layer 4 (64 -> 3) ----
    __syncthreads();
    hs[wid][lane] = h;
    __syncthreads();
    if (lane < 3) {
        float r = b4[lane];
        #pragma unroll 8
        for (int j = 0; j < 64; ++j) r = fmaf(hs[wid][j], W4[j * 3 + lane], r);
        rgb[(size_t)b * 3 + lane] = r;
    }
}

extern "C" void kernel_launch(void* const* d_in, const int* in_sizes, int n_in,
                              void* d_out, int out_size, void* d_ws, size_t ws_size,
                              hipStream_t stream) {
    const float* x    = (const float*)d_in[0];
    const float* tlab = (const float*)d_in[1];
    const float* trgb = (const float*)d_in[2];
    const float* wlab = (const float*)d_in[3];
    const float* blab = (const float*)d_in[4];
    const float* W1   = (const float*)d_in[5];
    const float* b1   = (const float*)d_in[6];
    const float* W2   = (const float*)d_in[7];
    const float* b2   = (const float*)d_in[8];
    const float* W3   = (const float*)d_in[9];
    const float* b3   = (const float*)d_in[10];
    const float* W4   = (const float*)d_in[11];
    const float* b4   = (const float*)d_in[12];

    const int B = in_sizes[0] / 4;  // 16384

    float* hits   = (float*)d_out;                       // [B]
    float* labels = hits + B;                            // [B*NS]
    float* rgbout = labels + (size_t)B * NS;             // [B*3]
    int* firsts   = (int*)d_ws;                          // [B]

    k_label<<<B, 256, 0, stream>>>(x, tlab, wlab, blab, hits, labels, firsts);
    k_rgb<<<B / 4, 256, 0, stream>>>(x, trgb, firsts,
                                     W1, b1, W2, b2, W3, b3, W4, b4, rgbout);
}